// Round 4
// baseline (8469.621 us; speedup 1.0000x reference)
//
#include <hip/hip_runtime.h>
#include <hip/hip_bf16.h>
#include <math.h>

// Dims: D=32, T=32, H=64, B=128, F=2048, 3F=6144, N=4096.
// Scan over axis 0 (128 sequential steps), state (32,2048). All I/O fp32.
// Round-4: hi/lo bf16 split precision (~17 mantissa bits) for all recurrence
// GEMM operands; fp32 gi + gate math. Rationale: recurrence amplifies bf16
// noise ~100-500x (round-3 absmax 0.105 = 256x the split-precision target).
//
// Workspace (bytes), total 161,873,920 (~154 MB):
//   WihH  [0,          25165824)  bf16 hi
//   WihL  [25165824,   50331648)  bf16 lo
//   WhhH  [50331648,   75497472)
//   WhhL  [75497472,  100663296)
//   gi    [100663296, 125829120)  fp32 (1024,6144) per 32-step phase
//   XYEhi [125829120, 142606336)  bf16 (4096,2048): X -> ys0 -> emb
//   XYElo [142606336, 159383552)
//   h32   [159383552, 159645696)  fp32 (32,2048)
//   z16   [159645696, 159776768)  bf16 zeros (t=0 state)
//   attv  [159776768, 160825344)  fp32 (128,2048)
//   gbuf  [160825344, 161873920)  fp32 (128,2048)
//   priors[0, 33554432) fp32 — overlaps Wih pair (dead at tail)

typedef __bf16 bf16;
typedef __attribute__((ext_vector_type(4))) __bf16 bf16x4;
typedef __attribute__((ext_vector_type(8))) __bf16 bf16x8;
typedef __attribute__((ext_vector_type(4))) float f32x4;

#define AS1 __attribute__((address_space(1)))
#define AS3 __attribute__((address_space(3)))

__device__ __forceinline__ void gll16(const void* g, void* s) {
  __builtin_amdgcn_global_load_lds((const AS1 void*)g, (AS3 void*)s, 16, 0, 0);
}
__device__ __forceinline__ float sigm(float x) { return 1.0f/(1.0f + expf(-x)); }
#define MFMA __builtin_amdgcn_mfma_f32_16x16x32_bf16

// ---------------- fp32 -> (hi, lo) bf16 split
__global__ __launch_bounds__(256) void k_split(const float4* __restrict__ in,
                                               bf16x4* __restrict__ hi,
                                               bf16x4* __restrict__ lo, int nvec) {
  int i = blockIdx.x*256 + threadIdx.x;
  if (i >= nvec) return;
  float4 v = in[i];
  bf16x4 h, l;
  h[0]=(bf16)v.x; l[0]=(bf16)(v.x-(float)h[0]);
  h[1]=(bf16)v.y; l[1]=(bf16)(v.y-(float)h[1]);
  h[2]=(bf16)v.z; l[2]=(bf16)(v.z-(float)h[2]);
  h[3]=(bf16)v.w; l[3]=(bf16)(v.w-(float)h[3]);
  hi[i] = h; lo[i] = l;
}

// ---------------- nan_to_num + split
__device__ __forceinline__ float fixv(float x) {
  if (isnan(x)) return 0.f;
  if (isinf(x)) return (x > 0.f) ? 1.0f : -3.4028234663852886e38f;
  return x;
}
__global__ __launch_bounds__(256) void k_prep(const float4* __restrict__ in,
                                              bf16x4* __restrict__ hi,
                                              bf16x4* __restrict__ lo, int nvec) {
  int i = blockIdx.x*256 + threadIdx.x;
  if (i >= nvec) return;
  float4 v = in[i];
  v.x = fixv(v.x); v.y = fixv(v.y); v.z = fixv(v.z); v.w = fixv(v.w);
  bf16x4 h, l;
  h[0]=(bf16)v.x; l[0]=(bf16)(v.x-(float)h[0]);
  h[1]=(bf16)v.y; l[1]=(bf16)(v.y-(float)h[1]);
  h[2]=(bf16)v.z; l[2]=(bf16)(v.z-(float)h[2]);
  h[3]=(bf16)v.w; l[3]=(bf16)(v.w-(float)h[3]);
  hi[i] = h; lo[i] = l;
}

// ---------------- C(M,N) fp32 = (Ah+Al)(M,K) @ (Bh+Bl)(N,K)^T + bias
// 3-term split-precision MFMA: AhBh + AlBh + AhBl. 128x128 tile, 4 waves, BK=64.
__global__ __launch_bounds__(256) void k_gemm3(
    const bf16* __restrict__ Ah, const bf16* __restrict__ Al,
    const bf16* __restrict__ Bh, const bf16* __restrict__ Bl,
    const float* __restrict__ bias, float* __restrict__ C,
    int M, int N, int K)
{
  __shared__ bf16x8 AsH[1024], AsL[1024], BsH[1024], BsL[1024];
  const int tid = threadIdx.x;
  const int w = tid >> 6, l = tid & 63;
  const int lm = l & 15, lk = l >> 4;
  const int m0 = blockIdx.y * 128, n0 = blockIdx.x * 128;
  const int wm = w & 1, wn = w >> 1;

  f32x4 acc[4][4];
#pragma unroll
  for (int i = 0; i < 4; i++)
#pragma unroll
    for (int j = 0; j < 4; j++) acc[i][j] = (f32x4){0.f,0.f,0.f,0.f};

  const int row_s = (w*64 + l) >> 3;
  const int s_s   = l & 7;

  for (int k0 = 0; k0 < K; k0 += 64) {
#pragma unroll
    for (int q = 0; q < 4; q++) {
      int row = q*32 + row_s;
      size_t offA = (size_t)(m0+row)*K + k0 + s_s*8;
      size_t offB = (size_t)(n0+row)*K + k0 + s_s*8;
      gll16(Ah + offA, &AsH[q*256 + w*64]);
      gll16(Al + offA, &AsL[q*256 + w*64]);
      gll16(Bh + offB, &BsH[q*256 + w*64]);
      gll16(Bl + offB, &BsL[q*256 + w*64]);
    }
    __syncthreads();
#pragma unroll
    for (int ko = 0; ko < 2; ko++) {
      const int kgl = ko*4 + lk;
      bf16x8 aFh[4], aFl[4], bFh[4], bFl[4];
#pragma unroll
      for (int mt = 0; mt < 4; mt++) {
        int r = (wm*64 + mt*16 + lm)*8 + kgl;
        aFh[mt] = AsH[r]; aFl[mt] = AsL[r];
      }
#pragma unroll
      for (int nt = 0; nt < 4; nt++) {
        int r = (wn*64 + nt*16 + lm)*8 + kgl;
        bFh[nt] = BsH[r]; bFl[nt] = BsL[r];
      }
#pragma unroll
      for (int mt = 0; mt < 4; mt++)
#pragma unroll
        for (int nt = 0; nt < 4; nt++) {
          acc[mt][nt] = MFMA(aFh[mt], bFh[nt], acc[mt][nt], 0,0,0);
          acc[mt][nt] = MFMA(aFl[mt], bFh[nt], acc[mt][nt], 0,0,0);
          acc[mt][nt] = MFMA(aFh[mt], bFl[nt], acc[mt][nt], 0,0,0);
        }
    }
    __syncthreads();
  }

  // C/D: col = lane&15, row = (lane>>4)*4 + reg
#pragma unroll
  for (int nt = 0; nt < 4; nt++) {
    int col = n0 + wn*64 + nt*16 + lm;
    float bv = bias[col];
#pragma unroll
    for (int mt = 0; mt < 4; mt++) {
      int rowb = m0 + wm*64 + mt*16 + lk*4;
#pragma unroll
      for (int r = 0; r < 4; r++)
        C[(size_t)(rowb + r)*N + col] = acc[mt][nt][r] + bv;
    }
  }
}

// ---------------- one GRU step, split precision.
// 256 blocks x 4 waves. Block owns 8 units; wave w covers K-slice [w*512,+512).
// gh = (hH+hL)@(WhH+WhL)^T via 3-term MFMA; LDS cross-wave reduce; wave 0 gates.
__global__ __launch_bounds__(256) void k_gru_step3(
    const bf16* __restrict__ WhH, const bf16* __restrict__ WhL,  // (6144,2048)
    const float* __restrict__ bhh,    // (6144)
    const float* __restrict__ gi_t,   // (32,6144) fp32, includes bih
    float* __restrict__ h32,          // (32,2048) fp32 master
    const bf16* __restrict__ aHi, const bf16* __restrict__ aLo,  // h_{t-1} (32,2048)
    bf16* __restrict__ oHi, bf16* __restrict__ oLo)              // h_t / ys_t
{
  __shared__ float red[4*64*25];
  const int tid = threadIdx.x;
  const int w = tid >> 6, l = tid & 63;
  const int lm = l & 15, lk = l >> 4;
  const int u0 = blockIdx.x * 8;
  const int ur = u0 + (lm & 7);     // B rows duplicated for lm>=8 (cols 8-15 = 0-7)

  f32x4 acc[2][3];
#pragma unroll
  for (int i = 0; i < 2; i++)
#pragma unroll
    for (int j = 0; j < 3; j++) acc[i][j] = (f32x4){0.f,0.f,0.f,0.f};

  const int kbase = w*512 + lk*8;
  const bf16* pah0 = aHi + lm*2048 + kbase;
  const bf16* pah1 = pah0 + 16*2048;
  const bf16* pal0 = aLo + lm*2048 + kbase;
  const bf16* pal1 = pal0 + 16*2048;
  const bf16* pbh[3], *pbl[3];
#pragma unroll
  for (int g = 0; g < 3; g++) {
    size_t off = ((size_t)(g*2048 + ur))*2048 + kbase;
    pbh[g] = WhH + off; pbl[g] = WhL + off;
  }

#pragma unroll 2
  for (int kb = 0; kb < 16; kb++) {
    int off = kb*32;
    bf16x8 ah0 = *(const bf16x8*)(pah0 + off);
    bf16x8 ah1 = *(const bf16x8*)(pah1 + off);
    bf16x8 al0 = *(const bf16x8*)(pal0 + off);
    bf16x8 al1 = *(const bf16x8*)(pal1 + off);
#pragma unroll
    for (int g = 0; g < 3; g++) {
      bf16x8 bh = *(const bf16x8*)(pbh[g] + off);
      bf16x8 bl = *(const bf16x8*)(pbl[g] + off);
      acc[0][g] = MFMA(ah0, bh, acc[0][g], 0,0,0);
      acc[0][g] = MFMA(al0, bh, acc[0][g], 0,0,0);
      acc[0][g] = MFMA(ah0, bl, acc[0][g], 0,0,0);
      acc[1][g] = MFMA(ah1, bh, acc[1][g], 0,0,0);
      acc[1][g] = MFMA(al1, bh, acc[1][g], 0,0,0);
      acc[1][g] = MFMA(ah1, bl, acc[1][g], 0,0,0);
    }
  }

  // cross-wave K-slice reduction
  float* myred = red + (w*64 + l)*25;
#pragma unroll
  for (int mt = 0; mt < 2; mt++)
#pragma unroll
    for (int g = 0; g < 3; g++)
#pragma unroll
      for (int r = 0; r < 4; r++) myred[(mt*3+g)*4 + r] = acc[mt][g][r];
  __syncthreads();
  if (w == 0) {
#pragma unroll
    for (int mt = 0; mt < 2; mt++)
#pragma unroll
      for (int g = 0; g < 3; g++)
#pragma unroll
        for (int r = 0; r < 4; r++) {
          int idx = (mt*3+g)*4 + r;
          acc[mt][g][r] = red[l*25 + idx] + red[(64+l)*25 + idx]
                        + red[(128+l)*25 + idx] + red[(192+l)*25 + idx];
        }
    if (lm < 8) {
      int u = u0 + lm;
      const float br_ = bhh[u], bz_ = bhh[2048 + u], bn_ = bhh[4096 + u];
#pragma unroll
      for (int mt = 0; mt < 2; mt++)
#pragma unroll
        for (int r = 0; r < 4; r++) {
          int row = mt*16 + lk*4 + r;
          const float* gir = gi_t + (size_t)row*6144;
          float rr = sigm(gir[u]        + acc[mt][0][r] + br_);
          float zz = sigm(gir[2048 + u] + acc[mt][1][r] + bz_);
          float nn = tanhf(gir[4096 + u] + rr*(acc[mt][2][r] + bn_));
          int idx = row*2048 + u;
          float hold = h32[idx];
          float hnew = (1.f - zz)*nn + zz*hold;
          h32[idx] = hnew;
          bf16 hb = (bf16)hnew;
          oHi[idx] = hb;
          oLo[idx] = (bf16)(hnew - (float)hb);
        }
    }
  }
}

// ---------------- temporal attention (reads emb hi+lo)
__global__ __launch_bounds__(256) void k_attn(
    const bf16* __restrict__ eHi, const bf16* __restrict__ eLo, // (128,32,2048)
    const float* __restrict__ A_w, const float* __restrict__ A_b,
    float* __restrict__ att_vec)    // (128,2048)
{
  __shared__ float Aw[1024];
  __shared__ float Ab[32];
  const int n = blockIdx.x, tid = threadIdx.x;
  for (int i = tid; i < 1024; i += 256) Aw[i] = A_w[i];
  if (tid < 32) Ab[tid] = A_b[tid];
  __syncthreads();
  for (int f = tid; f < 2048; f += 256) {
    float a[32];
#pragma unroll
    for (int t = 0; t < 32; t++) {
      size_t ix = (size_t)n*65536 + t*2048 + f;
      a[t] = tanhf((float)eHi[ix] + (float)eLo[ix]);
    }
    float aw[32]; float mx = -1e30f;
#pragma unroll
    for (int t2 = 0; t2 < 32; t2++) {
      float s = Ab[t2];
#pragma unroll
      for (int t = 0; t < 32; t++) s += Aw[t2*32 + t]*a[t];
      aw[t2] = s; mx = fmaxf(mx, s);
    }
    float den = 0.f, num = 0.f;
#pragma unroll
    for (int t = 0; t < 32; t++) { float e = expf(aw[t]-mx); den += e; num += e*a[t]; }
    att_vec[n*2048 + f] = tanhf(num/den);
  }
}

// ---------------- both GATv2 layers fused (fp32); block = 32-node dense subgraph
__global__ __launch_bounds__(256) void k_gat(
    const float* __restrict__ xn,
    const float* __restrict__ Wl0, const float* __restrict__ bl0,
    const float* __restrict__ Wr0, const float* __restrict__ br0,
    const float* __restrict__ at0, const float* __restrict__ bs0,
    const float* __restrict__ Wl1, const float* __restrict__ bl1,
    const float* __restrict__ Wr1, const float* __restrict__ br1,
    const float* __restrict__ at1, const float* __restrict__ bs1,
    float* __restrict__ gout)
{
  __shared__ float X[32*64];
  __shared__ float G0s[32*64];
  __shared__ float XL[32*65];
  __shared__ float XR[32*65];
  __shared__ float LG[32*32];
  __shared__ float WlT[64*64];
  __shared__ float WrT[64*64];
  __shared__ float attb[64], blb[64], brb[64], bsb[64];

  const int b = blockIdx.x, tid = threadIdx.x;
  for (int i = tid; i < 2048; i += 256) X[i] = xn[b*2048 + i];

  for (int lay = 0; lay < 2; lay++) {
    const float* Wl = lay ? Wl1 : Wl0;
    const float* Wr = lay ? Wr1 : Wr0;
    const float* bl = lay ? bl1 : bl0;
    const float* br = lay ? br1 : br0;
    const float* at = lay ? at1 : at0;
    const float* bs = lay ? bs1 : bs0;
    __syncthreads();
    for (int i = tid; i < 4096; i += 256) {
      int c = i >> 6, k = i & 63;
      WlT[k*64 + c] = Wl[i];
      WrT[k*64 + c] = Wr[i];
    }
    if (tid < 64) {
      attb[tid] = at[tid]; blb[tid] = bl[tid];
      brb[tid]  = br[tid]; bsb[tid] = bs[tid];
    }
    __syncthreads();
    const float* Xin = lay ? G0s : X;
    for (int e = tid; e < 2048; e += 256) {
      int i = e >> 6, c = e & 63;
      float sl = blb[c], sr = brb[c];
#pragma unroll 8
      for (int k = 0; k < 64; k++) {
        float xv = Xin[i*64 + k];
        sl += xv*WlT[k*64 + c];
        sr += xv*WrT[k*64 + c];
      }
      XL[i*65 + c] = sl; XR[i*65 + c] = sr;
    }
    __syncthreads();
    for (int p = tid; p < 1024; p += 256) {
      int i = p >> 5, j = p & 31;
      float s = 0.f;
#pragma unroll 8
      for (int c = 0; c < 64; c++) {
        float v = XL[i*65 + c] + XR[j*65 + c];
        v = (v > 0.f) ? v : 0.2f*v;
        s += v*attb[c];
      }
      LG[i*32 + j] = s;
    }
    __syncthreads();
    if (tid < 32) {
      int j = tid;
      float m = -1e30f;
      for (int i = 0; i < 32; i++) m = fmaxf(m, LG[i*32 + j]);
      float den = 0.f;
      for (int i = 0; i < 32; i++) den += expf(LG[i*32 + j] - m);
      float inv = 1.f/den;
      for (int i = 0; i < 32; i++) LG[i*32 + j] = expf(LG[i*32 + j] - m)*inv;
    }
    __syncthreads();
    for (int e = tid; e < 2048; e += 256) {
      int j = e >> 6, c = e & 63;
      float s = 0.f;
#pragma unroll 8
      for (int i = 0; i < 32; i++) s += LG[i*32 + j]*XL[i*65 + c];
      float val = tanhf(s + bsb[c]);
      if (lay == 0) G0s[j*64 + c] = val;
      else          gout[b*2048 + j*64 + c] = G0s[j*64 + c] + val;
    }
  }
}

// ---------------- priors[n,o,c,l] = sum_i W_caps[o,l,i]*fusion[n,c,i]
__global__ __launch_bounds__(256) void k_priors(
    const float* __restrict__ att_vec,
    const float* __restrict__ g,
    const float* __restrict__ W_caps,   // (32,64,128)
    float* __restrict__ priors)         // (128,32,32,64)
{
  __shared__ float FU[32*128];
  const int n = blockIdx.x >> 1, oh = blockIdx.x & 1, tid = threadIdx.x;
  for (int e = tid; e < 4096; e += 256) {
    int c = e >> 7, i = e & 127;
    FU[e] = (i < 64) ? att_vec[n*2048 + c*64 + i] : g[n*2048 + c*64 + (i - 64)];
  }
  __syncthreads();
  for (int oo = 0; oo < 16; oo++) {
    int o = oh*16 + oo;
    const float* W = W_caps + (size_t)o*8192;
    for (int e = tid; e < 2048; e += 256) {
      int c = e >> 6, l2 = e & 63;
      const float* Wr_ = W + l2*128;
      float s = 0.f;
#pragma unroll
      for (int i = 0; i < 128; i += 4) {
        float4 w4 = *(const float4*)(Wr_ + i);
        s += w4.x*FU[c*128 + i]     + w4.y*FU[c*128 + i + 1]
           + w4.z*FU[c*128 + i + 2] + w4.w*FU[c*128 + i + 3];
      }
      priors[(((size_t)n*32 + o)*32 + c)*64 + l2] = s;
    }
  }
}

// ---------------- dynamic routing (3 iters) + final FC
__global__ __launch_bounds__(64) void k_route(
    const float* __restrict__ priors,
    const float* __restrict__ F_w, const float* __restrict__ F_b,
    float* __restrict__ out)           // (128,32,32)
{
  __shared__ float ct[2048];
  __shared__ float fwt[2048];
  __shared__ float fbs[32];
  const int n = blockIdx.x, l = threadIdx.x;
  for (int i = l; i < 2048; i += 64) { int d2 = i >> 6, k = i & 63; fwt[k*32 + d2] = F_w[i]; }
  if (l < 32) fbs[l] = F_b[l];
  const float* PR = priors + (size_t)n*65536;

  float S[32];
#pragma unroll
  for (int o = 0; o < 32; o++) S[o] = 0.f;
  for (int c = 0; c < 32; c++) {
#pragma unroll
    for (int o = 0; o < 32; o++) S[o] += PR[(o*32 + c)*64 + l];
  }
#pragma unroll
  for (int o = 0; o < 32; o++) S[o] *= 0.03125f;

  float On[32];
  for (int rr = 0; rr < 2; rr++) {
#pragma unroll
    for (int o = 0; o < 32; o++) On[o] = 0.f;
    for (int c = 0; c < 32; c++) {
      float col[32], eo[32];
      float mx = -1e30f;
#pragma unroll
      for (int o = 0; o < 32; o++) {
        col[o] = PR[(o*32 + c)*64 + l];
        float t = col[o]*S[o];
        eo[o] = t; mx = fmaxf(mx, t);
      }
      float den = 0.f;
#pragma unroll
      for (int o = 0; o < 32; o++) { eo[o] = expf(eo[o]-mx); den += eo[o]; }
      float inv = 1.f/den;
#pragma unroll
      for (int o = 0; o < 32; o++) On[o] += eo[o]*inv*col[o];
    }
    if (rr == 0) {
#pragma unroll
      for (int o = 0; o < 32; o++) S[o] += On[o];
    }
  }
#pragma unroll
  for (int o = 0; o < 32; o++) ct[o*64 + l] = tanhf(On[o]);
  __syncthreads();
#pragma unroll
  for (int e = 0; e < 16; e++) {
    int el = l + e*64;
    int o = el >> 5, d2 = el & 31;
    float s = fbs[d2];
#pragma unroll
    for (int k = 0; k < 64; k++) s += ct[o*64 + k]*fwt[k*32 + d2];
    out[(size_t)n*1024 + el] = tanhf(s);
  }
}

// =====================================================================
extern "C" void kernel_launch(void* const* d_in, const int* in_sizes, int n_in,
                              void* d_out, int out_size, void* d_ws, size_t ws_size,
                              hipStream_t stream) {
  const float* inputs = (const float*)d_in[0];
  const float* Wih0 = (const float*)d_in[1];
  const float* Whh0 = (const float*)d_in[2];
  const float* bih0 = (const float*)d_in[3];
  const float* bhh0 = (const float*)d_in[4];
  const float* Wih1 = (const float*)d_in[5];
  const float* Whh1 = (const float*)d_in[6];
  const float* bih1 = (const float*)d_in[7];
  const float* bhh1 = (const float*)d_in[8];
  const float* A_w  = (const float*)d_in[9];
  const float* A_b  = (const float*)d_in[10];
  const float* g0_Wl = (const float*)d_in[11];
  const float* g0_bl = (const float*)d_in[12];
  const float* g0_Wr = (const float*)d_in[13];
  const float* g0_br = (const float*)d_in[14];
  const float* g0_at = (const float*)d_in[15];
  const float* g0_bs = (const float*)d_in[16];
  const float* g1_Wl = (const float*)d_in[17];
  const float* g1_bl = (const float*)d_in[18];
  const float* g1_Wr = (const float*)d_in[19];
  const float* g1_br = (const float*)d_in[20];
  const float* g1_at = (const float*)d_in[21];
  const float* g1_bs = (const float*)d_in[22];
  const float* W_caps = (const float*)d_in[23];
  const float* F_w  = (const float*)d_in[24];
  const float* F_b  = (const float*)d_in[25];
  // d_in[26] = edge_index: block-dense, not needed.

  char* ws = (char*)d_ws;
  bf16*  WihH  = (bf16*) (ws + 0);
  bf16*  WihL  = (bf16*) (ws + 25165824);
  bf16*  WhhH  = (bf16*) (ws + 50331648);
  bf16*  WhhL  = (bf16*) (ws + 75497472);
  float* gi    = (float*)(ws + 100663296);
  bf16*  XYEhi = (bf16*) (ws + 125829120);
  bf16*  XYElo = (bf16*) (ws + 142606336);
  float* h32   = (float*)(ws + 159383552);
  bf16*  z16   = (bf16*) (ws + 159645696);
  float* attv  = (float*)(ws + 159776768);
  float* g     = (float*)(ws + 160825344);
  float* priors= (float*)(ws + 0);          // overlaps Wih pair (dead at tail)

  dim3 gemm_grid(48, 8);   // N=6144/128, M=1024/128

  hipMemsetAsync(z16, 0, 131072, stream);
  k_prep<<<8192, 256, 0, stream>>>((const float4*)inputs, (bf16x4*)XYEhi, (bf16x4*)XYElo, 2097152);

  for (int layer = 0; layer < 2; layer++) {
    const float* Wih = layer ? Wih1 : Wih0;
    const float* Whh = layer ? Whh1 : Whh0;
    const float* bih = layer ? bih1 : bih0;
    const float* bhh = layer ? bhh1 : bhh0;

    k_split<<<12288, 256, 0, stream>>>((const float4*)Wih, (bf16x4*)WihH, (bf16x4*)WihL, 3145728);
    k_split<<<12288, 256, 0, stream>>>((const float4*)Whh, (bf16x4*)WhhH, (bf16x4*)WhhL, 3145728);
    hipMemsetAsync(h32, 0, 262144, stream);

    for (int p = 0; p < 4; p++) {
      k_gemm3<<<gemm_grid, 256, 0, stream>>>(
          XYEhi + (size_t)p*1024*2048, XYElo + (size_t)p*1024*2048,
          WihH, WihL, bih, gi, 1024, 6144, 2048);
      for (int tt = 0; tt < 32; tt++) {
        int t = p*32 + tt;
        const bf16* aHi = (t == 0) ? z16 : XYEhi + (size_t)(t-1)*65536;
        const bf16* aLo = (t == 0) ? z16 : XYElo + (size_t)(t-1)*65536;
        k_gru_step3<<<256, 256, 0, stream>>>(WhhH, WhhL, bhh,
            gi + (size_t)tt*196608, h32, aHi, aLo,
            XYEhi + (size_t)t*65536, XYElo + (size_t)t*65536);
      }
    }
  }

  // ---- tail (emb == XYE pair)
  k_attn<<<128, 256, 0, stream>>>(XYEhi, XYElo, A_w, A_b, attv);
  k_gat<<<128, 256, 0, stream>>>(attv,
      g0_Wl, g0_bl, g0_Wr, g0_br, g0_at, g0_bs,
      g1_Wl, g1_bl, g1_Wr, g1_br, g1_at, g1_bs, g);
  k_priors<<<256, 256, 0, stream>>>(attv, g, W_caps, priors);
  k_route<<<128, 64, 0, stream>>>(priors, F_w, F_b, (float*)d_out);
}